// Round 8
// baseline (197.317 us; speedup 1.0000x reference)
//
#include <hip/hip_runtime.h>
#include <math.h>

constexpr int B = 16, S = 512, D = 1024, H = 16, DH = 64;
constexpr int BH = B * H;        // 256

typedef short bf16x8 __attribute__((ext_vector_type(8)));
typedef float f32x4  __attribute__((ext_vector_type(4)));
typedef float f32x16 __attribute__((ext_vector_type(16)));

__device__ __forceinline__ unsigned short f2bf(float f) {
    unsigned u = __float_as_uint(f);
    u += 0x7fff + ((u >> 16) & 1);   // RNE
    return (unsigned short)(u >> 16);
}

#define VMC0  asm volatile("s_waitcnt vmcnt(0)" ::: "memory")
#define LGKM0 asm volatile("s_waitcnt lgkmcnt(0)" ::: "memory")
#define BARR  __builtin_amdgcn_s_barrier()

// ---------------------------------------------------------------------------
// MERGED converts:
//   blocks [0, 8192)    : x fp32 [B*S][D] -> xb bf16
//   blocks [8192, 8960) : W [3][H][D][DH] fp32 -> WbT [3][H][DH][D] bf16
// ---------------------------------------------------------------------------
__global__ __launch_bounds__(256) void convert_all(
    const float* __restrict__ x, unsigned short* __restrict__ xb,
    const float* __restrict__ Wq, const float* __restrict__ Wk,
    const float* __restrict__ Wv, unsigned short* __restrict__ WbT)
{
    __shared__ float tile[64][65];
    const int t = threadIdx.x;
    const int bx = blockIdx.x;

    if (bx < 8192) {
        int i = bx * 256 + t;
        float4 v = ((const float4*)x)[i];
        ushort4 o;
        o.x = f2bf(v.x); o.y = f2bf(v.y); o.z = f2bf(v.z); o.w = f2bf(v.w);
        ((ushort4*)xb)[i] = o;
        return;
    }

    const int cw = bx - 8192;               // 0..767
    const int d0 = (cw & 15) * 64;
    const int h = (cw >> 4) & 15;
    const int m = cw >> 8;                  // 0..2
    const float* W = ((m == 0) ? Wq : (m == 1) ? Wk : Wv) + (size_t)h * D * DH;
    {
        int e = t & 63, dr = t >> 6;
        #pragma unroll
        for (int i = 0; i < 16; ++i) {
            int d = dr * 16 + i;
            tile[d][e] = W[(size_t)(d0 + d) * DH + e];
        }
    }
    __syncthreads();
    {
        int d = t & 63, er = t >> 6;
        unsigned short* out = WbT + (size_t)(m * H + h) * DH * D;
        #pragma unroll
        for (int i = 0; i < 16; ++i) {
            int e = er * 16 + i;
            out[(size_t)e * D + d0 + d] = f2bf(tile[d][e]);
        }
    }
}

// ---------------------------------------------------------------------------
// Fused QKV projection — NOW 32x32x16 MFMA core (same 128x128 tile, 4 waves
// 2x2, wave 64x64 = 2x2 of 32x32; BK=64, 32 KB LDS, same XOR swizzle).
// Theory: VALUBusy(38) > MfmaUtil(28) = issue-bound; 32x32x16 halves MFMA
// instruction count at +20% FLOP/cyc (m119), same ds_read count.
// Fragment layouts (HW-verified mappings): A/B lane&31=row/col,
// k=(lane>>5)*8+j; C col=lane&31, row=(reg&3)+8*(reg>>2)+4*(lane>>5).
// Launched TWICE via n_base (qk: cols [0,2048); v: [2048,3072)) so that
// attn_mfma finally ranks in the top-5 and yields counters (diagnostic).
// q scaled by (1/sqrt(D))*log2e; v written transposed [bh][DH][S].
// ---------------------------------------------------------------------------
__global__ __launch_bounds__(256) void qkv_gemm(
    const unsigned short* __restrict__ xb,
    const unsigned short* __restrict__ WbT,
    unsigned short* __restrict__ qkvb, int n_base)
{
    __shared__ unsigned short As[128 * 64];   // 16 KB, swizzled g^(row&7)
    __shared__ unsigned short Bs[128 * 64];   // 16 KB

    const int t = threadIdx.x;
    const int w = t >> 6;
    const int wr = w >> 1, wc = w & 1;
    const int L = t & 63;
    const int lane31 = L & 31;
    const int hi = L >> 5;                    // k-half selector
    const int lrow8 = L >> 3;
    const int lg = L & 7;

    const int r0 = blockIdx.x * 128;          // global row (b*S+s)
    const int n0 = n_base + blockIdx.y * 128; // global col in [0, 3072)

    f32x16 acc[2][2] = {};

    for (int k0 = 0; k0 < D; k0 += 64) {
        #pragma unroll
        for (int i = 0; i < 4; ++i) {
            int c = w * 4 + i;
            int r = c * 8 + lrow8;
            int gg = lg ^ (r & 7);
            const unsigned short* gp = xb + (size_t)(r0 + r) * D + k0 + gg * 8;
            __builtin_amdgcn_global_load_lds(
                (const __attribute__((address_space(1))) void*)gp,
                (__attribute__((address_space(3))) void*)(As + c * 512),
                16, 0, 0);
            const unsigned short* gq = WbT + (size_t)(n0 + r) * D + k0 + gg * 8;
            __builtin_amdgcn_global_load_lds(
                (const __attribute__((address_space(1))) void*)gq,
                (__attribute__((address_space(3))) void*)(Bs + c * 512),
                16, 0, 0);
        }
        __syncthreads();

        #pragma unroll
        for (int ks4 = 0; ks4 < 4; ++ks4) {   // 4 k-slices of 16
            int g = ks4 * 2 + hi;             // 8-elem granule for this lane
            bf16x8 a[2], bb[2];
            #pragma unroll
            for (int rt = 0; rt < 2; ++rt) {
                int ml = wr * 64 + rt * 32 + lane31;
                a[rt] = *(const bf16x8*)(As + ml * 64 + ((g ^ (ml & 7)) * 8));
            }
            #pragma unroll
            for (int ct = 0; ct < 2; ++ct) {
                int nl = wc * 64 + ct * 32 + lane31;
                bb[ct] = *(const bf16x8*)(Bs + nl * 64 + ((g ^ (nl & 7)) * 8));
            }
            #pragma unroll
            for (int rt = 0; rt < 2; ++rt)
                #pragma unroll
                for (int ct = 0; ct < 2; ++ct)
                    acc[rt][ct] = __builtin_amdgcn_mfma_f32_32x32x16_bf16(
                        a[rt], bb[ct], acc[rt][ct], 0, 0, 0);
        }
        __syncthreads();
    }

    const int m  = n0 >> 10;                 // uniform per launch
    const int h  = ((n0 >> 6) + wc) & 15;    // one head per wave
    const int bb_ = r0 >> 9;                 // batch
    const int s0 = (r0 & 511) + wr * 64;

    if (m == 2) {
        unsigned short* outv = qkvb + ((size_t)(2 * BH) + (bb_ * H + h)) * (size_t)(S * DH);
        #pragma unroll
        for (int rt = 0; rt < 2; ++rt)
            #pragma unroll
            for (int ct = 0; ct < 2; ++ct) {
                int e = ct * 32 + lane31;
                #pragma unroll
                for (int rg = 0; rg < 4; ++rg) {       // reg-groups of 4 consec rows
                    int srow = s0 + rt * 32 + rg * 8 + hi * 4;
                    ushort4 pk;
                    pk.x = f2bf(acc[rt][ct][rg * 4 + 0]);
                    pk.y = f2bf(acc[rt][ct][rg * 4 + 1]);
                    pk.z = f2bf(acc[rt][ct][rg * 4 + 2]);
                    pk.w = f2bf(acc[rt][ct][rg * 4 + 3]);
                    *(ushort4*)(outv + (size_t)e * S + srow) = pk;
                }
            }
    } else {
        const float sc = (m == 0) ? 0.04508422002778011f : 1.0f; // (1/32)*log2e
        unsigned short* out = qkvb + ((size_t)m * BH + (bb_ * H + h)) * (size_t)(S * DH);
        #pragma unroll
        for (int rt = 0; rt < 2; ++rt)
            #pragma unroll
            for (int ct = 0; ct < 2; ++ct) {
                int e = ct * 32 + lane31;
                #pragma unroll
                for (int r = 0; r < 16; ++r) {
                    int srow = s0 + rt * 32 + (r & 3) + 8 * (r >> 2) + 4 * hi;
                    out[(size_t)srow * DH + e] = f2bf(acc[rt][ct][r] * sc);
                }
            }
    }
}

// ---------------------------------------------------------------------------
// Flash attention v7 (UNCHANGED from round 7 — byte-identical; with qkv
// split into ~49+25us launches, this kernel should now surface in the
// top-5 and yield its first real counters).
// ---------------------------------------------------------------------------
__global__ __launch_bounds__(512, 4) void attn_mfma(
    const unsigned short* __restrict__ qkvb, float* __restrict__ out)
{
    __shared__ unsigned short KV[2][2][64 * 64];   // 32 KB; [buf][0]=K, [buf][1]=V^T
    unsigned short* Qs = &KV[0][0][0];             // 16 KB overlay (buf 0)

    const int t = threadIdx.x;
    const int w = t >> 6;          // 0..7
    const int L = t & 63;
    const int lane15 = L & 15;
    const int quad = L >> 4;
    const int lrow8 = L >> 3;
    const int lg = L & 7;
    const int qr0 = blockIdx.x * 128;
    const int bh = blockIdx.y;
    const int b = bh >> 4, h = bh & 15;

    const unsigned short* qb = qkvb + (size_t)bh * S * DH;
    const unsigned short* kb = qkvb + (size_t)(BH + bh) * S * DH;
    const unsigned short* vt = qkvb + (size_t)(2 * BH + bh) * S * DH; // [64][512]

    // ---- stage Q (128 rows, 2 passes x 512 thr x 16B) into overlay ----
    #pragma unroll
    for (int p = 0; p < 2; ++p) {
        int base = p * 64 + w * 8;
        int r = base + lrow8;
        int gg = lg ^ (r & 7);
        __builtin_amdgcn_global_load_lds(
            (const __attribute__((address_space(1))) void*)
                (qb + (size_t)(qr0 + r) * DH + gg * 8),
            (__attribute__((address_space(3))) void*)(Qs + base * 64),
            16, 0, 0);
    }
    VMC0;
    BARR;

    // Q fragments to registers (wave w owns q-rows [qr0+w*16, +16))
    bf16x8 qf[2];
    #pragma unroll
    for (int ks = 0; ks < 2; ++ks) {
        int ml = w * 16 + lane15;
        int gk = ks * 4 + quad;
        qf[ks] = *(const bf16x8*)(Qs + ml * 64 + ((gk ^ (lane15 & 7)) * 8));
    }
    LGKM0;           // Q values in regs before any wave overwrites the overlay
    BARR;

    // ---- stage tile 0 into buf 0 (overwrites overlay; 2 gload_lds/wave) ----
    {
        int r = w * 8 + lrow8;
        int gr = (r & 32) | ((r & 12) << 1) | ((r & 16) >> 2) | (r & 3);
        int gg = lg ^ (r & 7);
        __builtin_amdgcn_global_load_lds(
            (const __attribute__((address_space(1))) void*)
                (kb + (size_t)gr * DH + gg * 8),
            (__attribute__((address_space(3))) void*)(&KV[0][0][0] + (w * 8) * 64),
            16, 0, 0);
        __builtin_amdgcn_global_load_lds(
            (const __attribute__((address_space(1))) void*)
                (vt + (size_t)r * S + gg * 8),
            (__attribute__((address_space(3))) void*)(&KV[0][1][0] + (w * 8) * 64),
            16, 0, 0);
    }
    VMC0;
    BARR;

    f32x4 o[4] = {};                 // rows = dh-slot, col = qrow(lane15)
    float plsum = 0.f;

    #pragma unroll 2
    for (int kt = 0; kt < 8; ++kt) {
        const int cur = kt & 1;
        const unsigned short* Kt  = &KV[cur][0][0];
        const unsigned short* Vtl = &KV[cur][1][0];

        // ---- S^T = K . Q^T (per-use kf loads; kf dead after this) ----
        f32x4 st[4] = {};
        #pragma unroll
        for (int ks = 0; ks < 2; ++ks) {
            int gk = ks * 4 + quad;
            bf16x8 kf[4];
            #pragma unroll
            for (int ct = 0; ct < 4; ++ct) {
                int kr = ct * 16 + lane15;
                kf[ct] = *(const bf16x8*)(Kt + kr * 64 + ((gk ^ (lane15 & 7)) * 8));
            }
            __builtin_amdgcn_s_setprio(1);
            #pragma unroll
            for (int ct = 0; ct < 4; ++ct)
                st[ct] = __builtin_amdgcn_mfma_f32_16x16x32_bf16(
                    kf[ct], qf[ks], st[ct], 0, 0, 0);
            __builtin_amdgcn_s_setprio(0);
        }

        // ---- p = exp2(s); cvt_pk into PV B-fragments; row partials ----
        bf16x8 pB[2];
        {
            float rs = 0.f;
            union { unsigned u[4]; bf16x8 v; } pu[2];
            #pragma unroll
            for (int ct = 0; ct < 4; ++ct) {
                float p0 = exp2f(st[ct][0]);
                float p1 = exp2f(st[ct][1]);
                float p2 = exp2f(st[ct][2]);
                float p3 = exp2f(st[ct][3]);
                rs += (p0 + p1) + (p2 + p3);
                unsigned lo, hi;
                asm("v_cvt_pk_bf16_f32 %0, %1, %2" : "=v"(lo) : "v"(p0), "v"(p1));
                asm("v_cvt_pk_bf16_f32 %0, %1, %2" : "=v"(hi) : "v"(p2), "v"(p3));
                pu[ct >> 1].u[(ct & 1) * 2 + 0] = lo;
                pu[ct >> 1].u[(ct & 1) * 2 + 1] = hi;
            }
            pB[0] = pu[0].v;
            pB[1] = pu[1].v;
            plsum += rs;
        }

        // ---- O^T += V^T . P^T (per-use vf loads) ----
        #pragma unroll
        for (int ks = 0; ks < 2; ++ks) {
            int gk = ks * 4 + quad;
            bf16x8 vf[4];
            #pragma unroll
            for (int nt = 0; nt < 4; ++nt) {
                int dh = nt * 16 + lane15;
                vf[nt] = *(const bf16x8*)(Vtl + dh * 64 + ((gk ^ (lane15 & 7)) * 8));
            }
            __builtin_amdgcn_s_setprio(1);
            #pragma unroll
            for (int nt = 0; nt < 4; ++nt)
                o[nt] = __builtin_amdgcn_mfma_f32_16x16x32_bf16(
                    vf[nt], pB[ks], o[nt], 0, 0, 0);
            __builtin_amdgcn_s_setprio(0);
        }

        // ---- stage next tile into buf cur^1, drain + barrier ----
        if (kt < 7) {
            int r = w * 8 + lrow8;
            int gr = (r & 32) | ((r & 12) << 1) | ((r & 16) >> 2) | (r & 3);
            int gg = lg ^ (r & 7);
            int kn = (kt + 1) * 64;
            __builtin_amdgcn_global_load_lds(
                (const __attribute__((address_space(1))) void*)
                    (kb + (size_t)(kn + gr) * DH + gg * 8),
                (__attribute__((address_space(3))) void*)(&KV[cur ^ 1][0][0] + (w * 8) * 64),
                16, 0, 0);
            __builtin_amdgcn_global_load_lds(
                (const __attribute__((address_space(1))) void*)
                    (vt + (size_t)r * S + kn + gg * 8),
                (__attribute__((address_space(3))) void*)(&KV[cur ^ 1][1][0] + (w * 8) * 64),
                16, 0, 0);
            VMC0;
            BARR;
        }
    }

    // epilogue: quad-reduce row sums, normalize, float4 stores (4 consec dh)
    {
        float l = plsum;
        l += __shfl_xor(l, 16, 64);
        l += __shfl_xor(l, 32, 64);
        float inv = 1.0f / l;
        int srow = qr0 + w * 16 + lane15;
        float* op = out + (size_t)(b * S + srow) * D + h * DH;
        #pragma unroll
        for (int nt = 0; nt < 4; ++nt) {
            float4 v;
            v.x = o[nt][0] * inv;
            v.y = o[nt][1] * inv;
            v.z = o[nt][2] * inv;
            v.w = o[nt][3] * inv;
            *(float4*)(op + nt * 16 + quad * 4) = v;
        }
    }
}

extern "C" void kernel_launch(void* const* d_in, const int* in_sizes, int n_in,
                              void* d_out, int out_size, void* d_ws, size_t ws_size,
                              hipStream_t stream) {
    const float* x  = (const float*)d_in[0];
    const float* Wq = (const float*)d_in[1];
    const float* Wk = (const float*)d_in[2];
    const float* Wv = (const float*)d_in[3];
    float* outp = (float*)d_out;

    // workspace: [0, 50331648) qkvb bf16 (q,k row-major; v transposed)
    //            [50331648, 67108864) xb bf16; [67108864, 73400320) WbT bf16
    unsigned short* qkvb = (unsigned short*)d_ws;
    unsigned short* xb   = (unsigned short*)((char*)d_ws + 50331648);
    unsigned short* WbT  = (unsigned short*)((char*)d_ws + 67108864);

    convert_all<<<dim3(8192 + 768), 256, 0, stream>>>(x, xb, Wq, Wk, Wv, WbT);
    qkv_gemm<<<dim3(B * S / 128, 16), 256, 0, stream>>>(xb, WbT, qkvb, 0);     // q,k
    qkv_gemm<<<dim3(B * S / 128, 8),  256, 0, stream>>>(xb, WbT, qkvb, 2048);  // v
    attn_mfma<<<dim3(S / 128, BH), 512, 0, stream>>>(qkvb, outp);
}

// Round 9
// 180.352 us; speedup vs baseline: 1.0941x; 1.0941x over previous
//
#include <hip/hip_runtime.h>
#include <math.h>

constexpr int B = 16, S = 512, D = 1024, H = 16, DH = 64;
constexpr int BH = B * H;        // 256

typedef short bf16x8 __attribute__((ext_vector_type(8)));
typedef float f32x4  __attribute__((ext_vector_type(4)));

__device__ __forceinline__ unsigned short f2bf(float f) {
    unsigned u = __float_as_uint(f);
    u += 0x7fff + ((u >> 16) & 1);   // RNE
    return (unsigned short)(u >> 16);
}

#define VMC0  asm volatile("s_waitcnt vmcnt(0)" ::: "memory")
#define LGKM0 asm volatile("s_waitcnt lgkmcnt(0)" ::: "memory")
#define BARR  __builtin_amdgcn_s_barrier()

// ---------------------------------------------------------------------------
// MERGED converts:
//   blocks [0, 8192)    : x fp32 [B*S][D] -> xb bf16
//   blocks [8192, 8960) : W [3][H][D][DH] fp32 -> WbT [3][H][DH][D] bf16
// ---------------------------------------------------------------------------
__global__ __launch_bounds__(256) void convert_all(
    const float* __restrict__ x, unsigned short* __restrict__ xb,
    const float* __restrict__ Wq, const float* __restrict__ Wk,
    const float* __restrict__ Wv, unsigned short* __restrict__ WbT)
{
    __shared__ float tile[64][65];
    const int t = threadIdx.x;
    const int bx = blockIdx.x;

    if (bx < 8192) {
        int i = bx * 256 + t;
        float4 v = ((const float4*)x)[i];
        ushort4 o;
        o.x = f2bf(v.x); o.y = f2bf(v.y); o.z = f2bf(v.z); o.w = f2bf(v.w);
        ((ushort4*)xb)[i] = o;
        return;
    }

    const int cw = bx - 8192;               // 0..767
    const int d0 = (cw & 15) * 64;
    const int h = (cw >> 4) & 15;
    const int m = cw >> 8;                  // 0..2
    const float* W = ((m == 0) ? Wq : (m == 1) ? Wk : Wv) + (size_t)h * D * DH;
    {
        int e = t & 63, dr = t >> 6;
        #pragma unroll
        for (int i = 0; i < 16; ++i) {
            int d = dr * 16 + i;
            tile[d][e] = W[(size_t)(d0 + d) * DH + e];
        }
    }
    __syncthreads();
    {
        int d = t & 63, er = t >> 6;
        unsigned short* out = WbT + (size_t)(m * H + h) * DH * D;
        #pragma unroll
        for (int i = 0; i < 16; ++i) {
            int e = er * 16 + i;
            out[(size_t)e * D + d0 + d] = f2bf(tile[d][e]);
        }
    }
}

// ---------------------------------------------------------------------------
// Fused QKV projection — round-0 kernel with ONE structural change:
// T3-minimum double-buffered pipeline. Per K-step: 16 ds_reads from
// buf[cur] FIRST, sched_barrier(0), issue next tile's 8 global_load_lds
// into buf[cur^1] (hides ~full compute under the load latency), 32 MFMA,
// then ONE vmcnt(0) (waits loads issued a compute-phase ago; ~0 residual)
// + ONE s_barrier. Round-0 had stage->drain->bar->compute->bar, where the
// stage of k+1 couldn't issue until compute(k) finished (same buffer) —
// full memory latency exposed serially every K-step (MfmaUtil 27%,
// active-occupancy 19% of resident: latency-bound, no pipe >40%).
// Hazards: step kt reads buf[cur] then writes buf[cur^1]; step kt-1's
// reads of buf[cur^1] were consumed (compiler lgkm before MFMA) before
// its end barrier, which all waves passed before kt's stage issues.
// 16x16x32 core (measured 0 bank conflicts), verified epilogues verbatim.
// 64 KB LDS -> 2 blocks/CU. Single launch again (split cost ~6us gap).
// q scaled by (1/sqrt(D))*log2e; v written transposed [bh][DH][S].
// ---------------------------------------------------------------------------
__device__ __forceinline__ void qkv_stage(
    const unsigned short* __restrict__ xb,
    const unsigned short* __restrict__ WbT,
    unsigned short* Ad, unsigned short* Bd,
    int r0, int n0, int k0, int w, int lrow8, int lg)
{
    #pragma unroll
    for (int i = 0; i < 4; ++i) {
        int c = w * 4 + i;
        int r = c * 8 + lrow8;
        int gg = lg ^ (r & 7);
        __builtin_amdgcn_global_load_lds(
            (const __attribute__((address_space(1))) void*)
                (xb + (size_t)(r0 + r) * D + k0 + gg * 8),
            (__attribute__((address_space(3))) void*)(Ad + c * 512),
            16, 0, 0);
        __builtin_amdgcn_global_load_lds(
            (const __attribute__((address_space(1))) void*)
                (WbT + (size_t)(n0 + r) * D + k0 + gg * 8),
            (__attribute__((address_space(3))) void*)(Bd + c * 512),
            16, 0, 0);
    }
}

__global__ __launch_bounds__(256) void qkv_gemm(
    const unsigned short* __restrict__ xb,
    const unsigned short* __restrict__ WbT,
    unsigned short* __restrict__ qkvb)
{
    __shared__ unsigned short As[2][128 * 64];   // 32 KB (dbuf)
    __shared__ unsigned short Bs[2][128 * 64];   // 32 KB (dbuf)

    const int t = threadIdx.x;
    const int w = t >> 6;
    const int wr = w >> 1, wc = w & 1;
    const int L = t & 63;
    const int lane15 = L & 15;
    const int quad = L >> 4;
    const int lrow8 = L >> 3;
    const int lg = L & 7;

    const int r0 = blockIdx.x * 128;   // global row (b*S+s)
    const int n0 = blockIdx.y * 128;   // global col in [0, 3072)

    f32x4 acc[4][4] = {};

    // prologue: stage tile 0 into buf 0, drain once
    qkv_stage(xb, WbT, &As[0][0], &Bs[0][0], r0, n0, 0, w, lrow8, lg);
    VMC0;
    BARR;

    #pragma unroll 2
    for (int kt = 0; kt < 16; ++kt) {
        const int cur = kt & 1;          // compile-time under unroll 2

        // ---- ds_reads of current tile FIRST (no LDS writes precede them) ----
        bf16x8 a[2][4], bb[2][4];
        #pragma unroll
        for (int ks = 0; ks < 2; ++ks) {
            int gk = ks * 4 + quad;
            #pragma unroll
            for (int rt = 0; rt < 4; ++rt) {
                int ml = wr * 64 + rt * 16 + lane15;
                a[ks][rt] = *(const bf16x8*)(&As[cur][0] + ml * 64 + ((gk ^ (ml & 7)) * 8));
            }
            #pragma unroll
            for (int ct = 0; ct < 4; ++ct) {
                int nl = wc * 64 + ct * 16 + lane15;
                bb[ks][ct] = *(const bf16x8*)(&Bs[cur][0] + nl * 64 + ((gk ^ (nl & 7)) * 8));
            }
        }
        __builtin_amdgcn_sched_barrier(0);   // pin: reads above, stage below

        // ---- issue next tile's stage into buf cur^1 (hidden under MFMAs) ----
        if (kt < 15)
            qkv_stage(xb, WbT, &As[cur ^ 1][0], &Bs[cur ^ 1][0],
                      r0, n0, (kt + 1) * 64, w, lrow8, lg);

        // ---- 32 MFMAs ----
        __builtin_amdgcn_s_setprio(1);
        #pragma unroll
        for (int ks = 0; ks < 2; ++ks)
            #pragma unroll
            for (int rt = 0; rt < 4; ++rt)
                #pragma unroll
                for (int ct = 0; ct < 4; ++ct)
                    acc[rt][ct] = __builtin_amdgcn_mfma_f32_16x16x32_bf16(
                        a[ks][rt], bb[ks][ct], acc[rt][ct], 0, 0, 0);
        __builtin_amdgcn_s_setprio(0);

        // ---- one wait (loads issued a compute-phase ago) + one barrier ----
        VMC0;
        BARR;
    }

    const int m  = n0 >> 10;                 // uniform per block
    const int h  = ((n0 >> 6) + wc) & 15;    // one head per wave
    const int bb_ = r0 >> 9;                 // batch
    const int s0 = (r0 & 511) + wr * 64;

    if (m == 2) {
        unsigned short* outv = qkvb + ((size_t)(2 * BH) + (bb_ * H + h)) * (size_t)(S * DH);
        #pragma unroll
        for (int rt = 0; rt < 4; ++rt) {
            int srow = s0 + rt * 16 + quad * 4;
            #pragma unroll
            for (int ct = 0; ct < 4; ++ct) {
                int e = ct * 16 + lane15;
                ushort4 pk;
                pk.x = f2bf(acc[rt][ct][0]);
                pk.y = f2bf(acc[rt][ct][1]);
                pk.z = f2bf(acc[rt][ct][2]);
                pk.w = f2bf(acc[rt][ct][3]);
                *(ushort4*)(outv + (size_t)e * S + srow) = pk;
            }
        }
    } else {
        const float sc = (m == 0) ? 0.04508422002778011f : 1.0f; // (1/32)*log2e
        unsigned short* out = qkvb + ((size_t)m * BH + (bb_ * H + h)) * (size_t)(S * DH);
        #pragma unroll
        for (int rt = 0; rt < 4; ++rt) {
            #pragma unroll
            for (int ct = 0; ct < 4; ++ct) {
                int e = ct * 16 + lane15;
                #pragma unroll
                for (int r = 0; r < 4; ++r) {
                    int srow = s0 + rt * 16 + quad * 4 + r;
                    out[(size_t)srow * DH + e] = f2bf(acc[rt][ct][r] * sc);
                }
            }
        }
    }
}

// ---------------------------------------------------------------------------
// Flash attention v7 (byte-identical to rounds 7/8).
// ---------------------------------------------------------------------------
__global__ __launch_bounds__(512, 4) void attn_mfma(
    const unsigned short* __restrict__ qkvb, float* __restrict__ out)
{
    __shared__ unsigned short KV[2][2][64 * 64];   // 32 KB; [buf][0]=K, [buf][1]=V^T
    unsigned short* Qs = &KV[0][0][0];             // 16 KB overlay (buf 0)

    const int t = threadIdx.x;
    const int w = t >> 6;          // 0..7
    const int L = t & 63;
    const int lane15 = L & 15;
    const int quad = L >> 4;
    const int lrow8 = L >> 3;
    const int lg = L & 7;
    const int qr0 = blockIdx.x * 128;
    const int bh = blockIdx.y;
    const int b = bh >> 4, h = bh & 15;

    const unsigned short* qb = qkvb + (size_t)bh * S * DH;
    const unsigned short* kb = qkvb + (size_t)(BH + bh) * S * DH;
    const unsigned short* vt = qkvb + (size_t)(2 * BH + bh) * S * DH; // [64][512]

    // ---- stage Q (128 rows, 2 passes x 512 thr x 16B) into overlay ----
    #pragma unroll
    for (int p = 0; p < 2; ++p) {
        int base = p * 64 + w * 8;
        int r = base + lrow8;
        int gg = lg ^ (r & 7);
        __builtin_amdgcn_global_load_lds(
            (const __attribute__((address_space(1))) void*)
                (qb + (size_t)(qr0 + r) * DH + gg * 8),
            (__attribute__((address_space(3))) void*)(Qs + base * 64),
            16, 0, 0);
    }
    VMC0;
    BARR;

    // Q fragments to registers (wave w owns q-rows [qr0+w*16, +16))
    bf16x8 qf[2];
    #pragma unroll
    for (int ks = 0; ks < 2; ++ks) {
        int ml = w * 16 + lane15;
        int gk = ks * 4 + quad;
        qf[ks] = *(const bf16x8*)(Qs + ml * 64 + ((gk ^ (lane15 & 7)) * 8));
    }
    LGKM0;           // Q values in regs before any wave overwrites the overlay
    BARR;

    // ---- stage tile 0 into buf 0 (overwrites overlay; 2 gload_lds/wave) ----
    {
        int r = w * 8 + lrow8;
        int gr = (r & 32) | ((r & 12) << 1) | ((r & 16) >> 2) | (r & 3);
        int gg = lg ^ (r & 7);
        __builtin_amdgcn_global_load_lds(
            (const __attribute__((address_space(1))) void*)
                (kb + (size_t)gr * DH + gg * 8),
            (__attribute__((address_space(3))) void*)(&KV[0][0][0] + (w * 8) * 64),
            16, 0, 0);
        __builtin_amdgcn_global_load_lds(
            (const __attribute__((address_space(1))) void*)
                (vt + (size_t)r * S + gg * 8),
            (__attribute__((address_space(3))) void*)(&KV[0][1][0] + (w * 8) * 64),
            16, 0, 0);
    }
    VMC0;
    BARR;

    f32x4 o[4] = {};                 // rows = dh-slot, col = qrow(lane15)
    float plsum = 0.f;

    #pragma unroll 2
    for (int kt = 0; kt < 8; ++kt) {
        const int cur = kt & 1;
        const unsigned short* Kt  = &KV[cur][0][0];
        const unsigned short* Vtl = &KV[cur][1][0];

        // ---- S^T = K . Q^T (per-use kf loads; kf dead after this) ----
        f32x4 st[4] = {};
        #pragma unroll
        for (int ks = 0; ks < 2; ++ks) {
            int gk = ks * 4 + quad;
            bf16x8 kf[4];
            #pragma unroll
            for (int ct = 0; ct < 4; ++ct) {
                int kr = ct * 16 + lane15;
                kf[ct] = *(const bf16x8*)(Kt + kr * 64 + ((gk ^ (lane15 & 7)) * 8));
            }
            __builtin_amdgcn_s_setprio(1);
            #pragma unroll
            for (int ct = 0; ct < 4; ++ct)
                st[ct] = __builtin_amdgcn_mfma_f32_16x16x32_bf16(
                    kf[ct], qf[ks], st[ct], 0, 0, 0);
            __builtin_amdgcn_s_setprio(0);
        }

        // ---- p = exp2(s); cvt_pk into PV B-fragments; row partials ----
        bf16x8 pB[2];
        {
            float rs = 0.f;
            union { unsigned u[4]; bf16x8 v; } pu[2];
            #pragma unroll
            for (int ct = 0; ct < 4; ++ct) {
                float p0 = exp2f(st[ct][0]);
                float p1 = exp2f(st[ct][1]);
                float p2 = exp2f(st[ct][2]);
                float p3 = exp2f(st[ct][3]);
                rs += (p0 + p1) + (p2 + p3);
                unsigned lo, hi;
                asm("v_cvt_pk_bf16_f32 %0, %1, %2" : "=v"(lo) : "v"(p0), "v"(p1));
                asm("v_cvt_pk_bf16_f32 %0, %1, %2" : "=v"(hi) : "v"(p2), "v"(p3));
                pu[ct >> 1].u[(ct & 1) * 2 + 0] = lo;
                pu[ct >> 1].u[(ct & 1) * 2 + 1] = hi;
            }
            pB[0] = pu[0].v;
            pB[1] = pu[1].v;
            plsum += rs;
        }

        // ---- O^T += V^T . P^T (per-use vf loads) ----
        #pragma unroll
        for (int ks = 0; ks < 2; ++ks) {
            int gk = ks * 4 + quad;
            bf16x8 vf[4];
            #pragma unroll
            for (int nt = 0; nt < 4; ++nt) {
                int dh = nt * 16 + lane15;
                vf[nt] = *(const bf16x8*)(Vtl + dh * 64 + ((gk ^ (lane15 & 7)) * 8));
            }
            __builtin_amdgcn_s_setprio(1);
            #pragma unroll
            for (int nt = 0; nt < 4; ++nt)
                o[nt] = __builtin_amdgcn_mfma_f32_16x16x32_bf16(
                    vf[nt], pB[ks], o[nt], 0, 0, 0);
            __builtin_amdgcn_s_setprio(0);
        }

        // ---- stage next tile into buf cur^1, drain + barrier ----
        if (kt < 7) {
            int r = w * 8 + lrow8;
            int gr = (r & 32) | ((r & 12) << 1) | ((r & 16) >> 2) | (r & 3);
            int gg = lg ^ (r & 7);
            int kn = (kt + 1) * 64;
            __builtin_amdgcn_global_load_lds(
                (const __attribute__((address_space(1))) void*)
                    (kb + (size_t)(kn + gr) * DH + gg * 8),
                (__attribute__((address_space(3))) void*)(&KV[cur ^ 1][0][0] + (w * 8) * 64),
                16, 0, 0);
            __builtin_amdgcn_global_load_lds(
                (const __attribute__((address_space(1))) void*)
                    (vt + (size_t)r * S + kn + gg * 8),
                (__attribute__((address_space(3))) void*)(&KV[cur ^ 1][1][0] + (w * 8) * 64),
                16, 0, 0);
            VMC0;
            BARR;
        }
    }

    // epilogue: quad-reduce row sums, normalize, float4 stores (4 consec dh)
    {
        float l = plsum;
        l += __shfl_xor(l, 16, 64);
        l += __shfl_xor(l, 32, 64);
        float inv = 1.0f / l;
        int srow = qr0 + w * 16 + lane15;
        float* op = out + (size_t)(b * S + srow) * D + h * DH;
        #pragma unroll
        for (int nt = 0; nt < 4; ++nt) {
            float4 v;
            v.x = o[nt][0] * inv;
            v.y = o[nt][1] * inv;
            v.z = o[nt][2] * inv;
            v.w = o[nt][3] * inv;
            *(float4*)(op + nt * 16 + quad * 4) = v;
        }
    }
}

extern "C" void kernel_launch(void* const* d_in, const int* in_sizes, int n_in,
                              void* d_out, int out_size, void* d_ws, size_t ws_size,
                              hipStream_t stream) {
    const float* x  = (const float*)d_in[0];
    const float* Wq = (const float*)d_in[1];
    const float* Wk = (const float*)d_in[2];
    const float* Wv = (const float*)d_in[3];
    float* outp = (float*)d_out;

    // workspace: [0, 50331648) qkvb bf16 (q,k row-major; v transposed)
    //            [50331648, 67108864) xb bf16; [67108864, 73400320) WbT bf16
    unsigned short* qkvb = (unsigned short*)d_ws;
    unsigned short* xb   = (unsigned short*)((char*)d_ws + 50331648);
    unsigned short* WbT  = (unsigned short*)((char*)d_ws + 67108864);

    convert_all<<<dim3(8192 + 768), 256, 0, stream>>>(x, xb, Wq, Wk, Wv, WbT);
    qkv_gemm<<<dim3(B * S / 128, 3 * H * DH / 128), 256, 0, stream>>>(xb, WbT, qkvb);
    attn_mfma<<<dim3(S / 128, BH), 512, 0, stream>>>(qkvb, outp);
}